// Round 2
// baseline (676.245 us; speedup 1.0000x reference)
//
#include <hip/hip_runtime.h>
#include <hip/hip_bf16.h>

#define HIDDEN 1024
#define FFN    2816
#define NEXP   8
#define NTOK   2048

typedef __attribute__((ext_vector_type(8))) short short8;   // 8 bf16 = 4 VGPRs
typedef __attribute__((ext_vector_type(4))) short bf16x4;   // 4 bf16 = 8 B
typedef __attribute__((ext_vector_type(4))) float f32x4;

static __device__ __forceinline__ short f2bf(float f) {
    __hip_bfloat16 h = __float2bfloat16(f);
    return *(short*)&h;
}

// async 16-B global->LDS DMA (lane i lands at ldsbase + i*16)
static __device__ __forceinline__ void gl_lds16(const short* g, short* l) {
    __builtin_amdgcn_global_load_lds(
        (const __attribute__((address_space(1))) void*)g,
        (__attribute__((address_space(3))) void*)l, 16, 0, 0);
}

// counted-vmcnt pipeline primitives (T3/T4): raw barrier, literal waitcnt
#define WAITV(N) asm volatile("s_waitcnt vmcnt(" #N ")" ::: "memory")
#define BAR()    do { __builtin_amdgcn_s_barrier(); \
                      __builtin_amdgcn_sched_barrier(0); } while (0)

// ---------------- Router body (shared by standalone + fused) -------------------
static __device__ __forceinline__ void
router_body(int t, int lane, const float* __restrict__ x,
            const float* __restrict__ Wgate, int* __restrict__ counts,
            int* __restrict__ tok, float* __restrict__ wts)
{
    float acc[NEXP];
#pragma unroll
    for (int e = 0; e < NEXP; e++) acc[e] = 0.f;
    const float* xrow = x + (size_t)t * HIDDEN;
    for (int h = lane; h < HIDDEN; h += 64) {
        float xv = xrow[h];
#pragma unroll
        for (int e = 0; e < NEXP; e++) acc[e] += xv * Wgate[e * HIDDEN + h];
    }
#pragma unroll
    for (int off = 32; off > 0; off >>= 1) {
#pragma unroll
        for (int e = 0; e < NEXP; e++) acc[e] += __shfl_down(acc[e], off);
    }
    if (lane == 0) {
        float mx = acc[0];
#pragma unroll
        for (int e = 1; e < NEXP; e++) mx = fmaxf(mx, acc[e]);
        float p[NEXP];
#pragma unroll
        for (int e = 0; e < NEXP; e++) p[e] = __expf(acc[e] - mx);
        int i0 = 0; float p0 = p[0];
#pragma unroll
        for (int e = 1; e < NEXP; e++) if (p[e] > p0) { p0 = p[e]; i0 = e; }
        int i1 = -1; float p1 = -1.f;
#pragma unroll
        for (int e = 0; e < NEXP; e++) {
            if (e == i0) continue;
            if (p[e] > p1) { p1 = p[e]; i1 = e; }
        }
        float inv = 1.f / (p0 + p1);
        float w0 = p0 * inv, w1 = p1 * inv;
        int s0 = atomicAdd(&counts[i0], 1);
        tok[i0 * NTOK + s0] = t; wts[i0 * NTOK + s0] = w0;
        int s1 = atomicAdd(&counts[i1], 1);
        tok[i1 * NTOK + s1] = t; wts[i1 * NTOK + s1] = w1;
    }
}

__global__ void __launch_bounds__(64)
router_kernel(const float* __restrict__ x, const float* __restrict__ Wgate,
              int* __restrict__ counts, int* __restrict__ tok,
              float* __restrict__ wts)
{
    router_body(blockIdx.x, threadIdx.x, x, Wgate, counts, tok, wts);
}

// ---------------- Fused router + dense-coalesced fp32->bf16 convert ------------
// Blocks [0,512): router, 4 waves = 4 tokens each.
// Blocks [512, 512+17408): convert.  Each block owns 1024 CONSECUTIVE float4s,
// processed in 4 dense phases (lane i reads f4[base + p*256 + i]) so every
// global_load_dwordx4 / store is lane-dense (16 B / 8 B per lane, stride 16/8).
// Segment sizes in float4 units are multiples of 1024 -> branch is block-uniform.
#define N04 ((long long)NTOK * HIDDEN / 4)          // 524288
#define NW4 ((long long)NEXP * FFN * HIDDEN / 4)    // 5767168
#define CVT_BLOCKS 17408                            // (N04 + 3*NW4) / 1024
__global__ void __launch_bounds__(256)
fused_cvt_router(const float* __restrict__ x, const float* __restrict__ Wgate,
                 int* __restrict__ counts, int* __restrict__ tok,
                 float* __restrict__ wts,
                 const float* __restrict__ s1, const float* __restrict__ s2,
                 const float* __restrict__ s3,
                 short* __restrict__ d0, short* __restrict__ d1,
                 short* __restrict__ d2, short* __restrict__ d3)
{
    int bid = blockIdx.x;
    int tid = threadIdx.x;
    if (bid < 512) {
        int t = bid * 4 + (tid >> 6);
        router_body(t, tid & 63, x, Wgate, counts, tok, wts);
        return;
    }
    long long base4 = (long long)(bid - 512) * 1024;
#pragma unroll
    for (int p = 0; p < 4; p++) {
        long long i = base4 + p * 256 + tid;
        const float* s; short* d; long long r;
        if (i < N04)               { s = x;  d = d0; r = i; }
        else if (i < N04 + NW4)    { s = s1; d = d1; r = i - N04; }
        else if (i < N04 + 2*NW4)  { s = s2; d = d2; r = i - N04 - NW4; }
        else                       { s = s3; d = d3; r = i - N04 - 2*NW4; }
        float4 a = ((const float4*)s)[r];
        bf16x4 o;
        o[0] = f2bf(a.x); o[1] = f2bf(a.y); o[2] = f2bf(a.z); o[3] = f2bf(a.w);
        *(bf16x4*)(d + 4 * r) = o;
    }
}

// ---------------- Stage A: 128x128 tile, triple-buffered counted-vmcnt pipeline -
// Grid order: (e, fb) outer, xb INNERMOST -> consecutive blocks share one
// 128-row weight strip; each strip is HBM-fetched ~once, xb-replays hit L2/L3.
__global__ void __launch_bounds__(256, 2)
ffn1_v5(const short* __restrict__ xbf, const short* __restrict__ Wgbf,
        const short* __restrict__ Wubf, const int* __restrict__ counts,
        const int* __restrict__ tok, short* __restrict__ hbuf)
{
    int bid = blockIdx.x;                 // 8 * 22 * 16 = 2816
    int e   = bid / 352;
    int rem = bid - e * 352;
    int fb  = rem >> 4;
    int xb  = rem & 15;
    int cnt = counts[e];
    int row0 = xb * 128;
    if (row0 >= cnt) return;
    int off_e = 0;
#pragma unroll
    for (int i = 0; i < NEXP; i++) if (i < e) off_e += counts[i];
    int f0 = fb * 128;

    __shared__ short Xs[3][128 * 32];
    __shared__ short Gs[3][128 * 32];
    __shared__ short Us[3][128 * 32];
    __shared__ int   stok[128];

    int tid = threadIdx.x;
    if (tid < 128) stok[tid] = tok[e * NTOK + min(row0 + tid, cnt - 1)];
    __syncthreads();

    int lane = tid & 63, w = tid >> 6;
    int l15 = lane & 15, lq = lane >> 4;
    int wm = (w & 1) * 64, wn = (w >> 1) * 64;

    // staging: wave w fills rows [w*32, w*32+32), 2 DMA instrs per tile each
    int prow   = lane >> 2;
    int gchunk = (lane & 3) ^ ((lane >> 3) & 3);      // swizzled source chunk
    const short* xsrc[2]; const short* gsrc[2]; const short* usrc[2];
    int rb[2];
#pragma unroll
    for (int j = 0; j < 2; j++) {
        int rbase = w * 32 + j * 16;
        int r = rbase + prow;
        xsrc[j] = xbf + (size_t)stok[r] * HIDDEN + gchunk * 8;
        gsrc[j] = Wgbf + (size_t)e * FFN * HIDDEN + (size_t)(f0 + r) * HIDDEN + gchunk * 8;
        usrc[j] = Wubf + (size_t)e * FFN * HIDDEN + (size_t)(f0 + r) * HIDDEN + gchunk * 8;
        rb[j] = rbase * 32;
    }

    // fragment LDS element offsets (row*32 + swizzled chunk*8)
    int aoff[4], boff[4];
#pragma unroll
    for (int mi = 0; mi < 4; mi++) {
        int r = wm + mi * 16 + l15;
        aoff[mi] = r * 32 + (lq ^ ((r >> 1) & 3)) * 8;
    }
#pragma unroll
    for (int ni = 0; ni < 4; ni++) {
        int r = wn + ni * 16 + l15;
        boff[ni] = r * 32 + (lq ^ ((r >> 1) & 3)) * 8;
    }

    f32x4 cg[4][4], cu[4][4];
#pragma unroll
    for (int i = 0; i < 4; i++)
#pragma unroll
        for (int j = 0; j < 4; j++) { cg[i][j] = (f32x4)0.f; cu[i][j] = (f32x4)0.f; }

#define STAGE1(B, T) do { int _k = (T) * 32;                       \
    _Pragma("unroll")                                              \
    for (int j = 0; j < 2; j++) {                                  \
        gl_lds16(xsrc[j] + _k, &Xs[B][rb[j]]);                     \
        gl_lds16(gsrc[j] + _k, &Gs[B][rb[j]]);                     \
        gl_lds16(usrc[j] + _k, &Us[B][rb[j]]);                     \
    } } while (0)

#define COMP1(B) do {                                              \
    short8 af[4], bg[4], bu[4];                                    \
    _Pragma("unroll")                                              \
    for (int mi = 0; mi < 4; mi++)                                 \
        af[mi] = *(const short8*)&Xs[B][aoff[mi]];                 \
    _Pragma("unroll")                                              \
    for (int ni = 0; ni < 4; ni++) {                               \
        bg[ni] = *(const short8*)&Gs[B][boff[ni]];                 \
        bu[ni] = *(const short8*)&Us[B][boff[ni]];                 \
    }                                                              \
    _Pragma("unroll")                                              \
    for (int mi = 0; mi < 4; mi++)                                 \
    _Pragma("unroll")                                              \
    for (int ni = 0; ni < 4; ni++) {                               \
        cg[mi][ni] = __builtin_amdgcn_mfma_f32_16x16x32_bf16(af[mi], bg[ni], cg[mi][ni], 0, 0, 0); \
        cu[mi][ni] = __builtin_amdgcn_mfma_f32_16x16x32_bf16(af[mi], bu[ni], cu[mi][ni], 0, 0, 0); \
    } } while (0)

    // prologue: 3 tiles in flight (18 outstanding DMAs/wave)
    STAGE1(0, 0); STAGE1(1, 1); STAGE1(2, 2);

    // main loop: t = 0..29 (NT=32).  wait vmcnt(12) == tiles t+1,t+2 in flight.
    for (int tt = 0; tt < 30; tt += 3) {
        WAITV(12); BAR(); COMP1(0); BAR(); STAGE1(0, tt + 3);
        WAITV(12); BAR(); COMP1(1); BAR(); STAGE1(1, tt + 4);
        WAITV(12); BAR(); COMP1(2); BAR(); if (tt + 5 < 32) STAGE1(2, tt + 5);
    }
    // peeled tail: t=30 (buf 0, one newer tile), t=31 (buf 1, none)
    WAITV(6);  BAR(); COMP1(0);
    WAITV(0);  BAR(); COMP1(1);

#undef STAGE1
#undef COMP1

    // epilogue: silu(g)*u -> bf16 hbuf.  C/D: col=lane&15, row=lq*4+reg
#pragma unroll
    for (int mi = 0; mi < 4; mi++)
#pragma unroll
        for (int r = 0; r < 4; r++) {
            int row = wm + mi * 16 + lq * 4 + r;
            int grow = row0 + row;
            if (grow < cnt) {
                short* hrow = hbuf + (size_t)(off_e + grow) * FFN + f0 + wn;
#pragma unroll
                for (int ni = 0; ni < 4; ni++) {
                    float g = cg[mi][ni][r], u = cu[mi][ni][r];
                    float h = g / (1.f + __expf(-g)) * u;
                    hrow[ni * 16 + l15] = f2bf(h);
                }
            }
        }
}

// ---------------- Stage B: 128x128 tile, K split in 2, same pipeline -----------
__global__ void __launch_bounds__(256, 2)
ffn2_v5(const short* __restrict__ hbuf, const short* __restrict__ Wdbf,
        const int* __restrict__ counts, const int* __restrict__ tok,
        const float* __restrict__ wts, float* __restrict__ out)
{
    int bid = blockIdx.x;                 // 8 * 16 * 16 = 2048
    int e   = bid >> 8;
    int rem = bid & 255;
    int y   = rem >> 4;
    int xb  = rem & 15;
    int cnt = counts[e];
    int row0 = xb * 128;
    if (row0 >= cnt) return;
    int off_e = 0;
#pragma unroll
    for (int i = 0; i < NEXP; i++) if (i < e) off_e += counts[i];
    int h0    = (y >> 1) * 128;
    int kbase = (y & 1) * (FFN / 2);

    __shared__ short Hs[3][128 * 32];
    __shared__ short Ds[3][128 * 32];
    __shared__ int   stok[128];
    __shared__ float swt[128];

    int tid = threadIdx.x;
    if (tid < 128) {
        int rc = min(row0 + tid, cnt - 1);
        stok[tid] = tok[e * NTOK + rc];
        swt[tid]  = wts[e * NTOK + rc];
    }
    __syncthreads();

    int lane = tid & 63, w = tid >> 6;
    int l15 = lane & 15, lq = lane >> 4;
    int wm = (w & 1) * 64, wn = (w >> 1) * 64;

    int prow   = lane >> 2;
    int gchunk = (lane & 3) ^ ((lane >> 3) & 3);
    const short* hsrc[2]; const short* dsrc[2];
    int rb[2];
#pragma unroll
    for (int j = 0; j < 2; j++) {
        int rbase = w * 32 + j * 16;
        int r = rbase + prow;
        hsrc[j] = hbuf + (size_t)(off_e + min(row0 + r, cnt - 1)) * FFN + kbase + gchunk * 8;
        dsrc[j] = Wdbf + (size_t)e * HIDDEN * FFN + (size_t)(h0 + r) * FFN + kbase + gchunk * 8;
        rb[j] = rbase * 32;
    }

    int aoff[4], boff[4];
#pragma unroll
    for (int mi = 0; mi < 4; mi++) {
        int r = wm + mi * 16 + l15;
        aoff[mi] = r * 32 + (lq ^ ((r >> 1) & 3)) * 8;
    }
#pragma unroll
    for (int ni = 0; ni < 4; ni++) {
        int r = wn + ni * 16 + l15;
        boff[ni] = r * 32 + (lq ^ ((r >> 1) & 3)) * 8;
    }

    f32x4 c[4][4];
#pragma unroll
    for (int i = 0; i < 4; i++)
#pragma unroll
        for (int j = 0; j < 4; j++) c[i][j] = (f32x4)0.f;

#define STAGE2(B, T) do { int _k = (T) * 32;                       \
    _Pragma("unroll")                                              \
    for (int j = 0; j < 2; j++) {                                  \
        gl_lds16(hsrc[j] + _k, &Hs[B][rb[j]]);                     \
        gl_lds16(dsrc[j] + _k, &Ds[B][rb[j]]);                     \
    } } while (0)

#define COMP2(B) do {                                              \
    short8 af[4], bd[4];                                           \
    _Pragma("unroll")                                              \
    for (int mi = 0; mi < 4; mi++)                                 \
        af[mi] = *(const short8*)&Hs[B][aoff[mi]];                 \
    _Pragma("unroll")                                              \
    for (int ni = 0; ni < 4; ni++)                                 \
        bd[ni] = *(const short8*)&Ds[B][boff[ni]];                 \
    _Pragma("unroll")                                              \
    for (int mi = 0; mi < 4; mi++)                                 \
    _Pragma("unroll")                                              \
    for (int ni = 0; ni < 4; ni++)                                 \
        c[mi][ni] = __builtin_amdgcn_mfma_f32_16x16x32_bf16(af[mi], bd[ni], c[mi][ni], 0, 0, 0); \
    } while (0)

    // NT = (FFN/2)/32 = 44 tiles; 4 DMAs/wave/tile -> wait vmcnt(8)
    STAGE2(0, 0); STAGE2(1, 1); STAGE2(2, 2);

    for (int tt = 0; tt < 42; tt += 3) {
        WAITV(8); BAR(); COMP2(0); BAR(); STAGE2(0, tt + 3);
        WAITV(8); BAR(); COMP2(1); BAR(); STAGE2(1, tt + 4);
        WAITV(8); BAR(); COMP2(2); BAR(); if (tt + 5 < 44) STAGE2(2, tt + 5);
    }
    WAITV(4); BAR(); COMP2(0);
    WAITV(0); BAR(); COMP2(1);

#undef STAGE2
#undef COMP2

#pragma unroll
    for (int mi = 0; mi < 4; mi++)
#pragma unroll
        for (int r = 0; r < 4; r++) {
            int row = wm + mi * 16 + lq * 4 + r;
            int grow = row0 + row;
            if (grow < cnt) {
                int t = stok[row];
                float wgt = swt[row];
                float* orow = out + (size_t)t * HIDDEN + h0 + wn;
#pragma unroll
                for (int ni = 0; ni < 4; ni++)
                    atomicAdd(&orow[ni * 16 + l15], wgt * c[mi][ni][r]);
            }
        }
}

// ================= Fallback path (R2 kernels, used if ws too small) ============
#define LDW 40
__global__ void __launch_bounds__(256, 2)
ffn1_fb(const float* __restrict__ x, const float* __restrict__ Wg,
        const float* __restrict__ Wu, const int* __restrict__ counts,
        const int* __restrict__ tok, __hip_bfloat16* __restrict__ hbuf)
{
    int e = blockIdx.z;
    int cnt = counts[e];
    int row0 = blockIdx.x * 128;
    if (row0 >= cnt) return;
    int off_e = 0;
#pragma unroll
    for (int i = 0; i < NEXP; i++) if (i < e) off_e += counts[i];
    int f0 = blockIdx.y * 64;

    __shared__ short Xs[128][LDW];
    __shared__ short Gs[64][LDW];
    __shared__ short Us[64][LDW];
    __shared__ int   stok[128];

    int tid = threadIdx.x;
    if (tid < 128) stok[tid] = tok[e * NTOK + min(row0 + tid, cnt - 1)];
    __syncthreads();

    int lane = tid & 63, w = tid >> 6;
    int wm = (w & 1) * 64, wn = (w >> 1) * 32;
    int l15 = lane & 15, lq = lane >> 4;

    f32x4 cg[4][2], cu[4][2];
#pragma unroll
    for (int i = 0; i < 4; i++)
#pragma unroll
        for (int j = 0; j < 2; j++) { cg[i][j] = (f32x4)0.f; cu[i][j] = (f32x4)0.f; }

    const float* Wge = Wg + (size_t)e * FFN * HIDDEN;
    const float* Wue = Wu + (size_t)e * FFN * HIDDEN;

    int xr[4], xc[4]; const float* xp[4];
#pragma unroll
    for (int i = 0; i < 4; i++) {
        int idx = tid + 256 * i;
        xr[i] = idx >> 3; xc[i] = (idx & 7) * 4;
        xp[i] = x + (size_t)stok[xr[i]] * HIDDEN + xc[i];
    }
    int wr[2], wc[2]; const float* gp[2]; const float* up[2];
#pragma unroll
    for (int i = 0; i < 2; i++) {
        int idx = tid + 256 * i;
        wr[i] = idx >> 3; wc[i] = (idx & 7) * 4;
        gp[i] = Wge + (size_t)(f0 + wr[i]) * HIDDEN + wc[i];
        up[i] = Wue + (size_t)(f0 + wr[i]) * HIDDEN + wc[i];
    }

    float4 xa[4], ga[2], ua[2];
#pragma unroll
    for (int i = 0; i < 4; i++) xa[i] = *(const float4*)(xp[i]);
#pragma unroll
    for (int i = 0; i < 2; i++) { ga[i] = *(const float4*)(gp[i]); ua[i] = *(const float4*)(up[i]); }

    for (int k0 = 0; k0 < HIDDEN; k0 += 32) {
        __syncthreads();
#pragma unroll
        for (int i = 0; i < 4; i++) {
            short* d = &Xs[xr[i]][xc[i]];
            d[0] = f2bf(xa[i].x); d[1] = f2bf(xa[i].y);
            d[2] = f2bf(xa[i].z); d[3] = f2bf(xa[i].w);
        }
#pragma unroll
        for (int i = 0; i < 2; i++) {
            short* d = &Gs[wr[i]][wc[i]];
            d[0] = f2bf(ga[i].x); d[1] = f2bf(ga[i].y);
            d[2] = f2bf(ga[i].z); d[3] = f2bf(ga[i].w);
            short* d2 = &Us[wr[i]][wc[i]];
            d2[0] = f2bf(ua[i].x); d2[1] = f2bf(ua[i].y);
            d2[2] = f2bf(ua[i].z); d2[3] = f2bf(ua[i].w);
        }
        __syncthreads();
        if (k0 + 32 < HIDDEN) {
            int kn = k0 + 32;
#pragma unroll
            for (int i = 0; i < 4; i++) xa[i] = *(const float4*)(xp[i] + kn);
#pragma unroll
            for (int i = 0; i < 2; i++) { ga[i] = *(const float4*)(gp[i] + kn); ua[i] = *(const float4*)(up[i] + kn); }
        }
        short8 af[4], bg[2], bu[2];
#pragma unroll
        for (int mi = 0; mi < 4; mi++) af[mi] = *(const short8*)&Xs[wm + mi * 16 + l15][lq * 8];
#pragma unroll
        for (int ni = 0; ni < 2; ni++) {
            bg[ni] = *(const short8*)&Gs[wn + ni * 16 + l15][lq * 8];
            bu[ni] = *(const short8*)&Us[wn + ni * 16 + l15][lq * 8];
        }
#pragma unroll
        for (int mi = 0; mi < 4; mi++)
#pragma unroll
            for (int ni = 0; ni < 2; ni++) {
                cg[mi][ni] = __builtin_amdgcn_mfma_f32_16x16x32_bf16(af[mi], bg[ni], cg[mi][ni], 0, 0, 0);
                cu[mi][ni] = __builtin_amdgcn_mfma_f32_16x16x32_bf16(af[mi], bu[ni], cu[mi][ni], 0, 0, 0);
            }
    }

#pragma unroll
    for (int mi = 0; mi < 4; mi++)
#pragma unroll
        for (int r = 0; r < 4; r++) {
            int row = wm + mi * 16 + lq * 4 + r;
            int grow = row0 + row;
            if (grow < cnt) {
                __hip_bfloat16* hrow = hbuf + (size_t)(off_e + grow) * FFN + f0 + wn;
#pragma unroll
                for (int ni = 0; ni < 2; ni++) {
                    float g = cg[mi][ni][r], u = cu[mi][ni][r];
                    float h = g / (1.f + __expf(-g)) * u;
                    hrow[ni * 16 + l15] = __float2bfloat16(h);
                }
            }
        }
}

__global__ void __launch_bounds__(256, 2)
ffn2_fb(const __hip_bfloat16* __restrict__ hbuf, const float* __restrict__ Wd,
        const int* __restrict__ counts, const int* __restrict__ tok,
        const float* __restrict__ wts, float* __restrict__ out)
{
    int e = blockIdx.z;
    int cnt = counts[e];
    int row0 = blockIdx.x * 128;
    if (row0 >= cnt) return;
    int off_e = 0;
#pragma unroll
    for (int i = 0; i < NEXP; i++) if (i < e) off_e += counts[i];
    int h0 = blockIdx.y * 64;

    __shared__ short Hs[128][LDW];
    __shared__ short Ds[64][LDW];
    __shared__ int   stok[128];
    __shared__ float swt[128];

    int tid = threadIdx.x;
    if (tid < 128) {
        int rc = min(row0 + tid, cnt - 1);
        stok[tid] = tok[e * NTOK + rc];
        swt[tid]  = wts[e * NTOK + rc];
    }
    __syncthreads();

    int lane = tid & 63, w = tid >> 6;
    int wm = (w & 1) * 64, wn = (w >> 1) * 32;
    int l15 = lane & 15, lq = lane >> 4;

    f32x4 c[4][2];
#pragma unroll
    for (int i = 0; i < 4; i++)
#pragma unroll
        for (int j = 0; j < 2; j++) c[i][j] = (f32x4)0.f;

    const float* Wde = Wd + (size_t)e * HIDDEN * FFN;

    int hr[2], hc[2]; const short* hp[2];
#pragma unroll
    for (int i = 0; i < 2; i++) {
        int idx = tid + 256 * i;
        hr[i] = idx >> 2; hc[i] = (idx & 3) * 8;
        int ar = min(row0 + hr[i], cnt - 1);
        hp[i] = (const short*)(hbuf + (size_t)(off_e + ar) * FFN + hc[i]);
    }
    int dr[2], dc[2]; const float* dp[2];
#pragma unroll
    for (int i = 0; i < 2; i++) {
        int idx = tid + 256 * i;
        dr[i] = idx >> 3; dc[i] = (idx & 7) * 4;
        dp[i] = Wde + (size_t)(h0 + dr[i]) * FFN + dc[i];
    }

    short8 ha[2]; float4 da[2];
#pragma unroll
    for (int i = 0; i < 2; i++) { ha[i] = *(const short8*)(hp[i]); da[i] = *(const float4*)(dp[i]); }

    for (int k0 = 0; k0 < FFN; k0 += 32) {
        __syncthreads();
#pragma unroll
        for (int i = 0; i < 2; i++) {
            *(short8*)&Hs[hr[i]][hc[i]] = ha[i];
            short* d = &Ds[dr[i]][dc[i]];
            d[0] = f2bf(da[i].x); d[1] = f2bf(da[i].y);
            d[2] = f2bf(da[i].z); d[3] = f2bf(da[i].w);
        }
        __syncthreads();
        if (k0 + 32 < FFN) {
            int kn = k0 + 32;
#pragma unroll
            for (int i = 0; i < 2; i++) { ha[i] = *(const short8*)(hp[i] + kn); da[i] = *(const float4*)(dp[i] + kn); }
        }
        short8 af[4], bf_[2];
#pragma unroll
        for (int mi = 0; mi < 4; mi++) af[mi] = *(const short8*)&Hs[wm + mi * 16 + l15][lq * 8];
#pragma unroll
        for (int ni = 0; ni < 2; ni++) bf_[ni] = *(const short8*)&Ds[wn + ni * 16 + l15][lq * 8];
#pragma unroll
        for (int mi = 0; mi < 4; mi++)
#pragma unroll
            for (int ni = 0; ni < 2; ni++)
                c[mi][ni] = __builtin_amdgcn_mfma_f32_16x16x32_bf16(af[mi], bf_[ni], c[mi][ni], 0, 0, 0);
    }

#pragma unroll
    for (int mi = 0; mi < 4; mi++)
#pragma unroll
        for (int r = 0; r < 4; r++) {
            int row = wm + mi * 16 + lq * 4 + r;
            int grow = row0 + row;
            if (grow < cnt) {
                int t = stok[row];
                float wgt = swt[row];
                float* orow = out + (size_t)t * HIDDEN + h0 + wn;
#pragma unroll
                for (int ni = 0; ni < 2; ni++)
                    atomicAdd(&orow[ni * 16 + l15], wgt * c[mi][ni][r]);
            }
        }
}

extern "C" void kernel_launch(void* const* d_in, const int* in_sizes, int n_in,
                              void* d_out, int out_size, void* d_ws, size_t ws_size,
                              hipStream_t stream) {
    const float* x     = (const float*)d_in[0];
    const float* Wgate = (const float*)d_in[1];
    const float* Wg    = (const float*)d_in[2];
    const float* Wu    = (const float*)d_in[3];
    const float* Wd    = (const float*)d_in[4];
    float* out = (float*)d_out;

    char* ws = (char*)d_ws;
    int*   counts = (int*)ws;
    int*   tok    = (int*)(ws + 256);
    float* wts    = (float*)(ws + 256 + NEXP * NTOK * 4);

    hipMemsetAsync(counts, 0, 256, stream);
    hipMemsetAsync(out, 0, (size_t)out_size * sizeof(float), stream);

    const size_t base = 256 + 2 * (size_t)NEXP * NTOK * 4;   // 131328
    const size_t NEED = base
        + 2ull * NTOK * HIDDEN                // xbf
        + 3ull * 2ull * NEXP * FFN * HIDDEN   // Wg/Wu/Wd bf16
        + 2ull * 2ull * NTOK * FFN;           // hbuf (4096 x 2816)

    if (ws_size >= NEED) {
        short* xbf  = (short*)(ws + base);
        short* wgbf = xbf  + (size_t)NTOK * HIDDEN;
        short* wubf = wgbf + (size_t)NEXP * FFN * HIDDEN;
        short* wdbf = wubf + (size_t)NEXP * FFN * HIDDEN;
        short* hbuf = wdbf + (size_t)NEXP * HIDDEN * FFN;

        // fused router (512 blocks) + dense-coalesced convert (17408 blocks)
        fused_cvt_router<<<512 + CVT_BLOCKS, 256, 0, stream>>>(
            x, Wgate, counts, tok, wts, Wg, Wu, Wd, xbf, wgbf, wubf, wdbf);

        ffn1_v5<<<2816, 256, 0, stream>>>(xbf, wgbf, wubf, counts, tok, hbuf);
        ffn2_v5<<<2048, 256, 0, stream>>>(hbuf, wdbf, counts, tok, wts, out);
    } else {
        router_kernel<<<NTOK, 64, 0, stream>>>(x, Wgate, counts, tok, wts);
        __hip_bfloat16* hbuf = (__hip_bfloat16*)(ws + base);
        dim3 g1(NTOK / 128, FFN / 64, NEXP);
        ffn1_fb<<<g1, 256, 0, stream>>>(x, Wg, Wu, counts, tok, hbuf);
        dim3 g2(NTOK / 128, HIDDEN / 64, NEXP);
        ffn2_fb<<<g2, 256, 0, stream>>>(hbuf, Wd, counts, tok, wts, out);
    }
}

// Round 3
// 448.530 us; speedup vs baseline: 1.5077x; 1.5077x over previous
//
#include <hip/hip_runtime.h>
#include <hip/hip_bf16.h>

#define HIDDEN 1024
#define FFN    2816
#define NEXP   8
#define NTOK   2048

typedef __attribute__((ext_vector_type(8))) short short8;   // 8 bf16 = 4 VGPRs
typedef __attribute__((ext_vector_type(4))) short bf16x4;   // 4 bf16 = 8 B
typedef __attribute__((ext_vector_type(4))) float f32x4;

static __device__ __forceinline__ short f2bf(float f) {
    __hip_bfloat16 h = __float2bfloat16(f);
    return *(short*)&h;
}

// async 16-B global->LDS DMA (lane i lands at ldsbase + i*16)
static __device__ __forceinline__ void gl_lds16(const short* g, short* l) {
    __builtin_amdgcn_global_load_lds(
        (const __attribute__((address_space(1))) void*)g,
        (__attribute__((address_space(3))) void*)l, 16, 0, 0);
}

// counted-vmcnt pipeline primitives (T3/T4): raw barrier, literal waitcnt
#define WAITV(N) asm volatile("s_waitcnt vmcnt(" #N ")" ::: "memory")
#define BAR()    do { __builtin_amdgcn_s_barrier(); \
                      __builtin_amdgcn_sched_barrier(0); } while (0)

// ---------------- Router body (shared by standalone + fused) -------------------
static __device__ __forceinline__ void
router_body(int t, int lane, const float* __restrict__ x,
            const float* __restrict__ Wgate, int* __restrict__ counts,
            int* __restrict__ tok, float* __restrict__ wts)
{
    float acc[NEXP];
#pragma unroll
    for (int e = 0; e < NEXP; e++) acc[e] = 0.f;
    const float* xrow = x + (size_t)t * HIDDEN;
    for (int h = lane; h < HIDDEN; h += 64) {
        float xv = xrow[h];
#pragma unroll
        for (int e = 0; e < NEXP; e++) acc[e] += xv * Wgate[e * HIDDEN + h];
    }
#pragma unroll
    for (int off = 32; off > 0; off >>= 1) {
#pragma unroll
        for (int e = 0; e < NEXP; e++) acc[e] += __shfl_down(acc[e], off);
    }
    if (lane == 0) {
        float mx = acc[0];
#pragma unroll
        for (int e = 1; e < NEXP; e++) mx = fmaxf(mx, acc[e]);
        float p[NEXP];
#pragma unroll
        for (int e = 0; e < NEXP; e++) p[e] = __expf(acc[e] - mx);
        int i0 = 0; float p0 = p[0];
#pragma unroll
        for (int e = 1; e < NEXP; e++) if (p[e] > p0) { p0 = p[e]; i0 = e; }
        int i1 = -1; float p1 = -1.f;
#pragma unroll
        for (int e = 0; e < NEXP; e++) {
            if (e == i0) continue;
            if (p[e] > p1) { p1 = p[e]; i1 = e; }
        }
        float inv = 1.f / (p0 + p1);
        float w0 = p0 * inv, w1 = p1 * inv;
        int s0 = atomicAdd(&counts[i0], 1);
        tok[i0 * NTOK + s0] = t; wts[i0 * NTOK + s0] = w0;
        int s1 = atomicAdd(&counts[i1], 1);
        tok[i1 * NTOK + s1] = t; wts[i1 * NTOK + s1] = w1;
    }
}

__global__ void __launch_bounds__(64)
router_kernel(const float* __restrict__ x, const float* __restrict__ Wgate,
              int* __restrict__ counts, int* __restrict__ tok,
              float* __restrict__ wts)
{
    router_body(blockIdx.x, threadIdx.x, x, Wgate, counts, tok, wts);
}

// ---------------- Fused router + dense-coalesced cvt of x, Wg, Wu --------------
// Blocks [0,512): router, 4 waves = 4 tokens each.
// Blocks [512, 512+11776): convert.  Each block owns 1024 CONSECUTIVE float4s,
// 4 dense phases (lane i reads f4[base + p*256 + i]); every load/store is
// lane-dense.  Segment sizes in float4 units are multiples of 1024 -> the
// segment branch is block-uniform.  Wd is converted inside ffn1_v6 (overlap).
#define N04  ((long long)NTOK * HIDDEN / 4)          // 524288
#define NW4  ((long long)NEXP * FFN * HIDDEN / 4)    // 5767168
#define CVTA_BLOCKS 11776                            // (N04 + 2*NW4) / 1024
__global__ void __launch_bounds__(256)
cvt_xgu_router(const float* __restrict__ x, const float* __restrict__ Wgate,
               int* __restrict__ counts, int* __restrict__ tok,
               float* __restrict__ wts,
               const float* __restrict__ s1, const float* __restrict__ s2,
               short* __restrict__ d0, short* __restrict__ d1,
               short* __restrict__ d2)
{
    int bid = blockIdx.x;
    int tid = threadIdx.x;
    if (bid < 512) {
        int t = bid * 4 + (tid >> 6);
        router_body(t, tid & 63, x, Wgate, counts, tok, wts);
        return;
    }
    long long base4 = (long long)(bid - 512) * 1024;
#pragma unroll
    for (int p = 0; p < 4; p++) {
        long long i = base4 + p * 256 + tid;
        const float* s; short* d; long long r;
        if (i < N04)            { s = x;  d = d0; r = i; }
        else if (i < N04 + NW4) { s = s1; d = d1; r = i - N04; }
        else                    { s = s2; d = d2; r = i - N04 - NW4; }
        float4 a = ((const float4*)s)[r];
        bf16x4 o;
        o[0] = f2bf(a.x); o[1] = f2bf(a.y); o[2] = f2bf(a.z); o[3] = f2bf(a.w);
        *(bf16x4*)(d + 4 * r) = o;
    }
}

// ---------------- Stage A: 128x128 tile, triple-buffered counted-vmcnt pipeline -
// Grid: bid = xb*176 + (e*22+fb), xb SLOWEST.  Live blocks (xb < ~4) form the
// contiguous range [0, 4*176) -> spread over all 8 XCDs; the 16 xb-replicas of a
// weight strip sit at stride 176 == 0 (mod 8) -> same XCD L2.  (Round-2 A/B:
// xb-fastest put all live blocks on XCDs 0-3 -> 2x slowdown.)
// Blocks [2816, 2816+2048): fp32->bf16 convert of Wd (independent of ffn1),
// soaking idle HBM bandwidth under the latency/compute-bound GEMM blocks.
#define FFN1_BLOCKS 2816
#define CVTD_BLOCKS 2048      // NW4 / (11*256)
__global__ void __launch_bounds__(256, 2)
ffn1_v6(const short* __restrict__ xbf, const short* __restrict__ Wgbf,
        const short* __restrict__ Wubf, const int* __restrict__ counts,
        const int* __restrict__ tok, short* __restrict__ hbuf,
        const float* __restrict__ Wd, short* __restrict__ wdbf)
{
    int bid = blockIdx.x;
    int tid = threadIdx.x;
    if (bid >= FFN1_BLOCKS) {
        // dense Wd convert: block owns 11*256 = 2816 consecutive float4s
        long long base4 = (long long)(bid - FFN1_BLOCKS) * 2816;
#pragma unroll
        for (int p = 0; p < 11; p++) {
            long long r = base4 + p * 256 + tid;
            float4 a = ((const float4*)Wd)[r];
            bf16x4 o;
            o[0] = f2bf(a.x); o[1] = f2bf(a.y); o[2] = f2bf(a.z); o[3] = f2bf(a.w);
            *(bf16x4*)(wdbf + 4 * r) = o;
        }
        return;
    }
    int xb  = bid / 176;
    int yz  = bid - xb * 176;
    int e   = yz / 22;
    int fb  = yz - e * 22;
    int cnt = counts[e];
    int row0 = xb * 128;
    if (row0 >= cnt) return;
    int off_e = 0;
#pragma unroll
    for (int i = 0; i < NEXP; i++) if (i < e) off_e += counts[i];
    int f0 = fb * 128;

    __shared__ short Xs[3][128 * 32];
    __shared__ short Gs[3][128 * 32];
    __shared__ short Us[3][128 * 32];
    __shared__ int   stok[128];

    if (tid < 128) stok[tid] = tok[e * NTOK + min(row0 + tid, cnt - 1)];
    __syncthreads();

    int lane = tid & 63, w = tid >> 6;
    int l15 = lane & 15, lq = lane >> 4;
    int wm = (w & 1) * 64, wn = (w >> 1) * 64;

    // staging: wave w fills rows [w*32, w*32+32), 2 DMA instrs per tile each
    int prow   = lane >> 2;
    int gchunk = (lane & 3) ^ ((lane >> 3) & 3);      // swizzled source chunk
    const short* xsrc[2]; const short* gsrc[2]; const short* usrc[2];
    int rb[2];
#pragma unroll
    for (int j = 0; j < 2; j++) {
        int rbase = w * 32 + j * 16;
        int r = rbase + prow;
        xsrc[j] = xbf + (size_t)stok[r] * HIDDEN + gchunk * 8;
        gsrc[j] = Wgbf + (size_t)e * FFN * HIDDEN + (size_t)(f0 + r) * HIDDEN + gchunk * 8;
        usrc[j] = Wubf + (size_t)e * FFN * HIDDEN + (size_t)(f0 + r) * HIDDEN + gchunk * 8;
        rb[j] = rbase * 32;
    }

    // fragment LDS element offsets (row*32 + swizzled chunk*8)
    int aoff[4], boff[4];
#pragma unroll
    for (int mi = 0; mi < 4; mi++) {
        int r = wm + mi * 16 + l15;
        aoff[mi] = r * 32 + (lq ^ ((r >> 1) & 3)) * 8;
    }
#pragma unroll
    for (int ni = 0; ni < 4; ni++) {
        int r = wn + ni * 16 + l15;
        boff[ni] = r * 32 + (lq ^ ((r >> 1) & 3)) * 8;
    }

    f32x4 cg[4][4], cu[4][4];
#pragma unroll
    for (int i = 0; i < 4; i++)
#pragma unroll
        for (int j = 0; j < 4; j++) { cg[i][j] = (f32x4)0.f; cu[i][j] = (f32x4)0.f; }

#define STAGE1(B, T) do { int _k = (T) * 32;                       \
    _Pragma("unroll")                                              \
    for (int j = 0; j < 2; j++) {                                  \
        gl_lds16(xsrc[j] + _k, &Xs[B][rb[j]]);                     \
        gl_lds16(gsrc[j] + _k, &Gs[B][rb[j]]);                     \
        gl_lds16(usrc[j] + _k, &Us[B][rb[j]]);                     \
    } } while (0)

#define COMP1(B) do {                                              \
    short8 af[4], bg[4], bu[4];                                    \
    _Pragma("unroll")                                              \
    for (int mi = 0; mi < 4; mi++)                                 \
        af[mi] = *(const short8*)&Xs[B][aoff[mi]];                 \
    _Pragma("unroll")                                              \
    for (int ni = 0; ni < 4; ni++) {                               \
        bg[ni] = *(const short8*)&Gs[B][boff[ni]];                 \
        bu[ni] = *(const short8*)&Us[B][boff[ni]];                 \
    }                                                              \
    _Pragma("unroll")                                              \
    for (int mi = 0; mi < 4; mi++)                                 \
    _Pragma("unroll")                                              \
    for (int ni = 0; ni < 4; ni++) {                               \
        cg[mi][ni] = __builtin_amdgcn_mfma_f32_16x16x32_bf16(af[mi], bg[ni], cg[mi][ni], 0, 0, 0); \
        cu[mi][ni] = __builtin_amdgcn_mfma_f32_16x16x32_bf16(af[mi], bu[ni], cu[mi][ni], 0, 0, 0); \
    } } while (0)

    // prologue: 3 tiles in flight (18 outstanding DMAs/wave)
    STAGE1(0, 0); STAGE1(1, 1); STAGE1(2, 2);

    // main loop: t = 0..29 (NT=32).  wait vmcnt(12) == tiles t+1,t+2 in flight.
    for (int tt = 0; tt < 30; tt += 3) {
        WAITV(12); BAR(); COMP1(0); BAR(); STAGE1(0, tt + 3);
        WAITV(12); BAR(); COMP1(1); BAR(); STAGE1(1, tt + 4);
        WAITV(12); BAR(); COMP1(2); BAR(); if (tt + 5 < 32) STAGE1(2, tt + 5);
    }
    // peeled tail: t=30 (buf 0, one newer tile), t=31 (buf 1, none)
    WAITV(6);  BAR(); COMP1(0);
    WAITV(0);  BAR(); COMP1(1);

#undef STAGE1
#undef COMP1

    // epilogue: silu(g)*u -> bf16 hbuf.  C/D: col=lane&15, row=lq*4+reg
#pragma unroll
    for (int mi = 0; mi < 4; mi++)
#pragma unroll
        for (int r = 0; r < 4; r++) {
            int row = wm + mi * 16 + lq * 4 + r;
            int grow = row0 + row;
            if (grow < cnt) {
                short* hrow = hbuf + (size_t)(off_e + grow) * FFN + f0 + wn;
#pragma unroll
                for (int ni = 0; ni < 4; ni++) {
                    float g = cg[mi][ni][r], u = cu[mi][ni][r];
                    float h = g / (1.f + __expf(-g)) * u;
                    hrow[ni * 16 + l15] = f2bf(h);
                }
            }
        }
}

// ---------------- Stage B: 128x128 tile, K split in 2, same pipeline -----------
// Grid: bid = xb*128 + (e*16+y), xb SLOWEST (same XCD argument; 128 % 8 == 0).
__global__ void __launch_bounds__(256, 2)
ffn2_v6(const short* __restrict__ hbuf, const short* __restrict__ Wdbf,
        const int* __restrict__ counts, const int* __restrict__ tok,
        const float* __restrict__ wts, float* __restrict__ out)
{
    int bid = blockIdx.x;
    int xb  = bid >> 7;
    int yz  = bid & 127;
    int e   = yz >> 4;
    int y   = yz & 15;
    int cnt = counts[e];
    int row0 = xb * 128;
    if (row0 >= cnt) return;
    int off_e = 0;
#pragma unroll
    for (int i = 0; i < NEXP; i++) if (i < e) off_e += counts[i];
    int h0    = (y >> 1) * 128;
    int kbase = (y & 1) * (FFN / 2);

    __shared__ short Hs[3][128 * 32];
    __shared__ short Ds[3][128 * 32];
    __shared__ int   stok[128];
    __shared__ float swt[128];

    int tid = threadIdx.x;
    if (tid < 128) {
        int rc = min(row0 + tid, cnt - 1);
        stok[tid] = tok[e * NTOK + rc];
        swt[tid]  = wts[e * NTOK + rc];
    }
    __syncthreads();

    int lane = tid & 63, w = tid >> 6;
    int l15 = lane & 15, lq = lane >> 4;
    int wm = (w & 1) * 64, wn = (w >> 1) * 64;

    int prow   = lane >> 2;
    int gchunk = (lane & 3) ^ ((lane >> 3) & 3);
    const short* hsrc[2]; const short* dsrc[2];
    int rb[2];
#pragma unroll
    for (int j = 0; j < 2; j++) {
        int rbase = w * 32 + j * 16;
        int r = rbase + prow;
        hsrc[j] = hbuf + (size_t)(off_e + min(row0 + r, cnt - 1)) * FFN + kbase + gchunk * 8;
        dsrc[j] = Wdbf + (size_t)e * HIDDEN * FFN + (size_t)(h0 + r) * FFN + kbase + gchunk * 8;
        rb[j] = rbase * 32;
    }

    int aoff[4], boff[4];
#pragma unroll
    for (int mi = 0; mi < 4; mi++) {
        int r = wm + mi * 16 + l15;
        aoff[mi] = r * 32 + (lq ^ ((r >> 1) & 3)) * 8;
    }
#pragma unroll
    for (int ni = 0; ni < 4; ni++) {
        int r = wn + ni * 16 + l15;
        boff[ni] = r * 32 + (lq ^ ((r >> 1) & 3)) * 8;
    }

    f32x4 c[4][4];
#pragma unroll
    for (int i = 0; i < 4; i++)
#pragma unroll
        for (int j = 0; j < 4; j++) c[i][j] = (f32x4)0.f;

#define STAGE2(B, T) do { int _k = (T) * 32;                       \
    _Pragma("unroll")                                              \
    for (int j = 0; j < 2; j++) {                                  \
        gl_lds16(hsrc[j] + _k, &Hs[B][rb[j]]);                     \
        gl_lds16(dsrc[j] + _k, &Ds[B][rb[j]]);                     \
    } } while (0)

#define COMP2(B) do {                                              \
    short8 af[4], bd[4];                                           \
    _Pragma("unroll")                                              \
    for (int mi = 0; mi < 4; mi++)                                 \
        af[mi] = *(const short8*)&Hs[B][aoff[mi]];                 \
    _Pragma("unroll")                                              \
    for (int ni = 0; ni < 4; ni++)                                 \
        bd[ni] = *(const short8*)&Ds[B][boff[ni]];                 \
    _Pragma("unroll")                                              \
    for (int mi = 0; mi < 4; mi++)                                 \
    _Pragma("unroll")                                              \
    for (int ni = 0; ni < 4; ni++)                                 \
        c[mi][ni] = __builtin_amdgcn_mfma_f32_16x16x32_bf16(af[mi], bd[ni], c[mi][ni], 0, 0, 0); \
    } while (0)

    // NT = (FFN/2)/32 = 44 tiles; 4 DMAs/wave/tile -> wait vmcnt(8)
    STAGE2(0, 0); STAGE2(1, 1); STAGE2(2, 2);

    for (int tt = 0; tt < 42; tt += 3) {
        WAITV(8); BAR(); COMP2(0); BAR(); STAGE2(0, tt + 3);
        WAITV(8); BAR(); COMP2(1); BAR(); STAGE2(1, tt + 4);
        WAITV(8); BAR(); COMP2(2); BAR(); if (tt + 5 < 44) STAGE2(2, tt + 5);
    }
    WAITV(4); BAR(); COMP2(0);
    WAITV(0); BAR(); COMP2(1);

#undef STAGE2
#undef COMP2

#pragma unroll
    for (int mi = 0; mi < 4; mi++)
#pragma unroll
        for (int r = 0; r < 4; r++) {
            int row = wm + mi * 16 + lq * 4 + r;
            int grow = row0 + row;
            if (grow < cnt) {
                int t = stok[row];
                float wgt = swt[row];
                float* orow = out + (size_t)t * HIDDEN + h0 + wn;
#pragma unroll
                for (int ni = 0; ni < 4; ni++)
                    atomicAdd(&orow[ni * 16 + l15], wgt * c[mi][ni][r]);
            }
        }
}

// ================= Fallback path (R2 kernels, used if ws too small) ============
#define LDW 40
__global__ void __launch_bounds__(256, 2)
ffn1_fb(const float* __restrict__ x, const float* __restrict__ Wg,
        const float* __restrict__ Wu, const int* __restrict__ counts,
        const int* __restrict__ tok, __hip_bfloat16* __restrict__ hbuf)
{
    int e = blockIdx.z;
    int cnt = counts[e];
    int row0 = blockIdx.x * 128;
    if (row0 >= cnt) return;
    int off_e = 0;
#pragma unroll
    for (int i = 0; i < NEXP; i++) if (i < e) off_e += counts[i];
    int f0 = blockIdx.y * 64;

    __shared__ short Xs[128][LDW];
    __shared__ short Gs[64][LDW];
    __shared__ short Us[64][LDW];
    __shared__ int   stok[128];

    int tid = threadIdx.x;
    if (tid < 128) stok[tid] = tok[e * NTOK + min(row0 + tid, cnt - 1)];
    __syncthreads();

    int lane = tid & 63, w = tid >> 6;
    int wm = (w & 1) * 64, wn = (w >> 1) * 32;
    int l15 = lane & 15, lq = lane >> 4;

    f32x4 cg[4][2], cu[4][2];
#pragma unroll
    for (int i = 0; i < 4; i++)
#pragma unroll
        for (int j = 0; j < 2; j++) { cg[i][j] = (f32x4)0.f; cu[i][j] = (f32x4)0.f; }

    const float* Wge = Wg + (size_t)e * FFN * HIDDEN;
    const float* Wue = Wu + (size_t)e * FFN * HIDDEN;

    int xr[4], xc[4]; const float* xp[4];
#pragma unroll
    for (int i = 0; i < 4; i++) {
        int idx = tid + 256 * i;
        xr[i] = idx >> 3; xc[i] = (idx & 7) * 4;
        xp[i] = x + (size_t)stok[xr[i]] * HIDDEN + xc[i];
    }
    int wr[2], wc[2]; const float* gp[2]; const float* up[2];
#pragma unroll
    for (int i = 0; i < 2; i++) {
        int idx = tid + 256 * i;
        wr[i] = idx >> 3; wc[i] = (idx & 7) * 4;
        gp[i] = Wge + (size_t)(f0 + wr[i]) * HIDDEN + wc[i];
        up[i] = Wue + (size_t)(f0 + wr[i]) * HIDDEN + wc[i];
    }

    float4 xa[4], ga[2], ua[2];
#pragma unroll
    for (int i = 0; i < 4; i++) xa[i] = *(const float4*)(xp[i]);
#pragma unroll
    for (int i = 0; i < 2; i++) { ga[i] = *(const float4*)(gp[i]); ua[i] = *(const float4*)(up[i]); }

    for (int k0 = 0; k0 < HIDDEN; k0 += 32) {
        __syncthreads();
#pragma unroll
        for (int i = 0; i < 4; i++) {
            short* d = &Xs[xr[i]][xc[i]];
            d[0] = f2bf(xa[i].x); d[1] = f2bf(xa[i].y);
            d[2] = f2bf(xa[i].z); d[3] = f2bf(xa[i].w);
        }
#pragma unroll
        for (int i = 0; i < 2; i++) {
            short* d = &Gs[wr[i]][wc[i]];
            d[0] = f2bf(ga[i].x); d[1] = f2bf(ga[i].y);
            d[2] = f2bf(ga[i].z); d[3] = f2bf(ga[i].w);
            short* d2 = &Us[wr[i]][wc[i]];
            d2[0] = f2bf(ua[i].x); d2[1] = f2bf(ua[i].y);
            d2[2] = f2bf(ua[i].z); d2[3] = f2bf(ua[i].w);
        }
        __syncthreads();
        if (k0 + 32 < HIDDEN) {
            int kn = k0 + 32;
#pragma unroll
            for (int i = 0; i < 4; i++) xa[i] = *(const float4*)(xp[i] + kn);
#pragma unroll
            for (int i = 0; i < 2; i++) { ga[i] = *(const float4*)(gp[i] + kn); ua[i] = *(const float4*)(up[i] + kn); }
        }
        short8 af[4], bg[2], bu[2];
#pragma unroll
        for (int mi = 0; mi < 4; mi++) af[mi] = *(const short8*)&Xs[wm + mi * 16 + l15][lq * 8];
#pragma unroll
        for (int ni = 0; ni < 2; ni++) {
            bg[ni] = *(const short8*)&Gs[wn + ni * 16 + l15][lq * 8];
            bu[ni] = *(const short8*)&Us[wn + ni * 16 + l15][lq * 8];
        }
#pragma unroll
        for (int mi = 0; mi < 4; mi++)
#pragma unroll
            for (int ni = 0; ni < 2; ni++) {
                cg[mi][ni] = __builtin_amdgcn_mfma_f32_16x16x32_bf16(af[mi], bg[ni], cg[mi][ni], 0, 0, 0);
                cu[mi][ni] = __builtin_amdgcn_mfma_f32_16x16x32_bf16(af[mi], bu[ni], cu[mi][ni], 0, 0, 0);
            }
    }

#pragma unroll
    for (int mi = 0; mi < 4; mi++)
#pragma unroll
        for (int r = 0; r < 4; r++) {
            int row = wm + mi * 16 + lq * 4 + r;
            int grow = row0 + row;
            if (grow < cnt) {
                __hip_bfloat16* hrow = hbuf + (size_t)(off_e + grow) * FFN + f0 + wn;
#pragma unroll
                for (int ni = 0; ni < 2; ni++) {
                    float g = cg[mi][ni][r], u = cu[mi][ni][r];
                    float h = g / (1.f + __expf(-g)) * u;
                    hrow[ni * 16 + l15] = __float2bfloat16(h);
                }
            }
        }
}

__global__ void __launch_bounds__(256, 2)
ffn2_fb(const __hip_bfloat16* __restrict__ hbuf, const float* __restrict__ Wd,
        const int* __restrict__ counts, const int* __restrict__ tok,
        const float* __restrict__ wts, float* __restrict__ out)
{
    int e = blockIdx.z;
    int cnt = counts[e];
    int row0 = blockIdx.x * 128;
    if (row0 >= cnt) return;
    int off_e = 0;
#pragma unroll
    for (int i = 0; i < NEXP; i++) if (i < e) off_e += counts[i];
    int h0 = blockIdx.y * 64;

    __shared__ short Hs[128][LDW];
    __shared__ short Ds[64][LDW];
    __shared__ int   stok[128];
    __shared__ float swt[128];

    int tid = threadIdx.x;
    if (tid < 128) {
        int rc = min(row0 + tid, cnt - 1);
        stok[tid] = tok[e * NTOK + rc];
        swt[tid]  = wts[e * NTOK + rc];
    }
    __syncthreads();

    int lane = tid & 63, w = tid >> 6;
    int wm = (w & 1) * 64, wn = (w >> 1) * 32;
    int l15 = lane & 15, lq = lane >> 4;

    f32x4 c[4][2];
#pragma unroll
    for (int i = 0; i < 4; i++)
#pragma unroll
        for (int j = 0; j < 2; j++) c[i][j] = (f32x4)0.f;

    const float* Wde = Wd + (size_t)e * HIDDEN * FFN;

    int hr[2], hc[2]; const short* hp[2];
#pragma unroll
    for (int i = 0; i < 2; i++) {
        int idx = tid + 256 * i;
        hr[i] = idx >> 2; hc[i] = (idx & 3) * 8;
        int ar = min(row0 + hr[i], cnt - 1);
        hp[i] = (const short*)(hbuf + (size_t)(off_e + ar) * FFN + hc[i]);
    }
    int dr[2], dc[2]; const float* dp[2];
#pragma unroll
    for (int i = 0; i < 2; i++) {
        int idx = tid + 256 * i;
        dr[i] = idx >> 3; dc[i] = (idx & 7) * 4;
        dp[i] = Wde + (size_t)(h0 + dr[i]) * FFN + dc[i];
    }

    short8 ha[2]; float4 da[2];
#pragma unroll
    for (int i = 0; i < 2; i++) { ha[i] = *(const short8*)(hp[i]); da[i] = *(const float4*)(dp[i]); }

    for (int k0 = 0; k0 < FFN; k0 += 32) {
        __syncthreads();
#pragma unroll
        for (int i = 0; i < 2; i++) {
            *(short8*)&Hs[hr[i]][hc[i]] = ha[i];
            short* d = &Ds[dr[i]][dc[i]];
            d[0] = f2bf(da[i].x); d[1] = f2bf(da[i].y);
            d[2] = f2bf(da[i].z); d[3] = f2bf(da[i].w);
        }
        __syncthreads();
        if (k0 + 32 < FFN) {
            int kn = k0 + 32;
#pragma unroll
            for (int i = 0; i < 2; i++) { ha[i] = *(const short8*)(hp[i] + kn); da[i] = *(const float4*)(dp[i] + kn); }
        }
        short8 af[4], bf_[2];
#pragma unroll
        for (int mi = 0; mi < 4; mi++) af[mi] = *(const short8*)&Hs[wm + mi * 16 + l15][lq * 8];
#pragma unroll
        for (int ni = 0; ni < 2; ni++) bf_[ni] = *(const short8*)&Ds[wn + ni * 16 + l15][lq * 8];
#pragma unroll
        for (int mi = 0; mi < 4; mi++)
#pragma unroll
            for (int ni = 0; ni < 2; ni++)
                c[mi][ni] = __builtin_amdgcn_mfma_f32_16x16x32_bf16(af[mi], bf_[ni], c[mi][ni], 0, 0, 0);
    }

#pragma unroll
    for (int mi = 0; mi < 4; mi++)
#pragma unroll
        for (int r = 0; r < 4; r++) {
            int row = wm + mi * 16 + lq * 4 + r;
            int grow = row0 + row;
            if (grow < cnt) {
                int t = stok[row];
                float wgt = swt[row];
                float* orow = out + (size_t)t * HIDDEN + h0 + wn;
#pragma unroll
                for (int ni = 0; ni < 2; ni++)
                    atomicAdd(&orow[ni * 16 + l15], wgt * c[mi][ni][r]);
            }
        }
}

extern "C" void kernel_launch(void* const* d_in, const int* in_sizes, int n_in,
                              void* d_out, int out_size, void* d_ws, size_t ws_size,
                              hipStream_t stream) {
    const float* x     = (const float*)d_in[0];
    const float* Wgate = (const float*)d_in[1];
    const float* Wg    = (const float*)d_in[2];
    const float* Wu    = (const float*)d_in[3];
    const float* Wd    = (const float*)d_in[4];
    float* out = (float*)d_out;

    char* ws = (char*)d_ws;
    int*   counts = (int*)ws;
    int*   tok    = (int*)(ws + 256);
    float* wts    = (float*)(ws + 256 + NEXP * NTOK * 4);

    hipMemsetAsync(counts, 0, 256, stream);
    hipMemsetAsync(out, 0, (size_t)out_size * sizeof(float), stream);

    const size_t base = 256 + 2 * (size_t)NEXP * NTOK * 4;   // 131328
    const size_t NEED = base
        + 2ull * NTOK * HIDDEN                // xbf
        + 3ull * 2ull * NEXP * FFN * HIDDEN   // Wg/Wu/Wd bf16
        + 2ull * 2ull * NTOK * FFN;           // hbuf (4096 x 2816)

    if (ws_size >= NEED) {
        short* xbf  = (short*)(ws + base);
        short* wgbf = xbf  + (size_t)NTOK * HIDDEN;
        short* wubf = wgbf + (size_t)NEXP * FFN * HIDDEN;
        short* wdbf = wubf + (size_t)NEXP * FFN * HIDDEN;
        short* hbuf = wdbf + (size_t)NEXP * HIDDEN * FFN;

        // fused router (512 blocks) + dense cvt of x/Wg/Wu (11776 blocks)
        cvt_xgu_router<<<512 + CVTA_BLOCKS, 256, 0, stream>>>(
            x, Wgate, counts, tok, wts, Wg, Wu, xbf, wgbf, wubf);

        // ffn1 (2816 blocks, xb-slowest order) + Wd cvt mop-up (2048 blocks)
        ffn1_v6<<<FFN1_BLOCKS + CVTD_BLOCKS, 256, 0, stream>>>(
            xbf, wgbf, wubf, counts, tok, hbuf, Wd, wdbf);

        ffn2_v6<<<2048, 256, 0, stream>>>(hbuf, wdbf, counts, tok, wts, out);
    } else {
        router_kernel<<<NTOK, 64, 0, stream>>>(x, Wgate, counts, tok, wts);
        __hip_bfloat16* hbuf = (__hip_bfloat16*)(ws + base);
        dim3 g1(NTOK / 128, FFN / 64, NEXP);
        ffn1_fb<<<g1, 256, 0, stream>>>(x, Wg, Wu, counts, tok, hbuf);
        dim3 g2(NTOK / 128, HIDDEN / 64, NEXP);
        ffn2_fb<<<g2, 256, 0, stream>>>(hbuf, Wd, counts, tok, wts, out);
    }
}